// Round 1
// baseline (135.499 us; speedup 1.0000x reference)
//
#include <hip/hip_runtime.h>
#include <math.h>

namespace {
constexpr int D = 256;
constexpr int H = 8;
constexpr int HD = 32;
constexpr int B = 8;
constexpr int S = 127;
constexpr int N = 128;
constexpr float LN_EPS = 1e-5f;

// ws layout (float offsets). P1T/P2T are stored PACKED:
// element (b, c, i) at (b*64 + (c>>2))*512 + i*4 + (c&3)  -> float4 over c for fixed i.
constexpr int WS_P1T = 0;                  // B*D*N
constexpr int WS_P2T = WS_P1T + B * D * N; // B*D*N
constexpr int WS_V   = WS_P2T + B * D * N; // B*N*D (row-major)
constexpr int WS_AQ  = WS_V + B * N * D;   // B*H*N
constexpr int WS_AK  = WS_AQ + B * H * N;  // B*H*N
constexpr int WS_FQK = WS_AK + B * H * N;  // D*16 (wq-fold | wk-fold)
constexpr int WS_V2  = WS_FQK + D * 16;    // H*D (transposed: [h][c])
constexpr int WS_BF  = WS_V2 + D * H;      // 32 (bq-fold[8], bk-fold[8], be-fold[8])

union F4 { float4 v; float f[4]; };
} // namespace

// K1: fold wq/wk with attn_w[:32]/[32:64] -> FQK (D x 16), ew2 with attn_w[64:96] -> V2T (H x D),
//     plus bias folds.
__global__ __launch_bounds__(256) void k1_fold(
    const float* __restrict__ wq, const float* __restrict__ wk,
    const float* __restrict__ ew2, const float* __restrict__ bq,
    const float* __restrict__ bk, const float* __restrict__ eb2,
    const float* __restrict__ attn_w, float* __restrict__ ws) {
  float* FQK = ws + WS_FQK;
  float* V2T = ws + WS_V2;
  float* BF  = ws + WS_BF;
  const int mat = blockIdx.x;            // 0: wq, 1: wk, 2: ew2
  const float* W = (mat == 0) ? wq : (mat == 1) ? wk : ew2;
  const float* aw = attn_w + mat * HD;
  const int t = threadIdx.x;
  const int d = t & 31;
  const int rl = t >> 5;                 // 8 rows per iteration
  const float a = aw[d];
  for (int c0 = 0; c0 < D; c0 += 8) {
    const int c = c0 + rl;
    float p[8];
#pragma unroll
    for (int h = 0; h < 8; ++h) p[h] = W[c * D + h * HD + d] * a;
#pragma unroll
    for (int h = 0; h < 8; ++h) {
#pragma unroll
      for (int o = 16; o >= 1; o >>= 1) p[h] += __shfl_xor(p[h], o, 32);
    }
    if (d == 0) {
#pragma unroll
      for (int h = 0; h < 8; ++h) {
        if (mat < 2) FQK[c * 16 + mat * 8 + h] = p[h];
        else         V2T[h * D + c] = p[h];
      }
    }
  }
  if (t < 8) {
    const float* bias = (mat == 0) ? bq : (mat == 1) ? bk : eb2;
    float pb = 0.f;
    for (int d2 = 0; d2 < HD; ++d2) pb = fmaf(bias[t * HD + d2], aw[d2], pb);
    BF[mat * 8 + t] = pb;
  }
}

// K2: P1 = desc @ ew1[:D], P2 = desc @ ew1[D:], written packed-transposed.
// grid: B * 16 blocks (8 desc rows each), 256 threads (thread = output col c).
__global__ __launch_bounds__(256) void k2_pmat(
    const float* __restrict__ desc, const float* __restrict__ ew1,
    float* __restrict__ ws) {
  float* P1Tf = ws + WS_P1T;
  float* P2Tf = ws + WS_P2T;
  const int b = blockIdx.x >> 4;
  const int i0 = (blockIdx.x & 15) * 8;
  const int t = threadIdx.x;
  __shared__ float dl[8][260];
  for (int k = t; k < 8 * D; k += 256) {
    const int r = k >> 8, c = k & (D - 1);
    const int row = i0 + r;
    dl[r][c] = (row < S) ? desc[(b * S + row) * D + c] : 0.f;
  }
  __syncthreads();
  float a1[8], a2[8];
#pragma unroll
  for (int ii = 0; ii < 8; ++ii) { a1[ii] = 0.f; a2[ii] = 0.f; }
  for (int c2 = 0; c2 < D; c2 += 4) {
    float w1[4], w2[4];
#pragma unroll
    for (int e = 0; e < 4; ++e) {
      w1[e] = ew1[(c2 + e) * D + t];
      w2[e] = ew1[(D + c2 + e) * D + t];
    }
#pragma unroll
    for (int ii = 0; ii < 8; ++ii) {
      F4 dv; dv.v = *(const float4*)&dl[ii][c2];
#pragma unroll
      for (int e = 0; e < 4; ++e) {
        a1[ii] = fmaf(dv.f[e], w1[e], a1[ii]);
        a2[ii] = fmaf(dv.f[e], w2[e], a2[ii]);
      }
    }
  }
  const int pbase = (b * 64 + (t >> 2)) * 512 + (t & 3);
#pragma unroll
  for (int ii = 0; ii < 8; ++ii) {
    if (i0 + ii < S) {
      P1Tf[pbase + (i0 + ii) * 4] = a1[ii];
      P2Tf[pbase + (i0 + ii) * 4] = a2[ii];
    }
  }
}

// K3: v = nv @ wv + bv (row-major), aq/ak via folded weights.
// grid: B * 16 blocks (8 nv rows each), 256 threads.
__global__ __launch_bounds__(256) void k3_qkv(
    const float* __restrict__ nv, const float* __restrict__ wv,
    const float* __restrict__ bv, float* __restrict__ ws) {
  float* Vf  = ws + WS_V;
  float* AQ  = ws + WS_AQ;
  float* AK  = ws + WS_AK;
  const float* FQK = ws + WS_FQK;
  const float* BF  = ws + WS_BF;
  const int b = blockIdx.x >> 4;
  const int j0 = (blockIdx.x & 15) * 8;
  const int t = threadIdx.x;
  __shared__ float nl[8][260];
  for (int k = t; k < 8 * D; k += 256) {
    const int r = k >> 8, c = k & (D - 1);
    nl[r][c] = nv[(b * N + j0 + r) * D + c];
  }
  __syncthreads();
  float acc[8];
#pragma unroll
  for (int jj = 0; jj < 8; ++jj) acc[jj] = 0.f;
  for (int c2 = 0; c2 < D; c2 += 4) {
    float wvv[4];
#pragma unroll
    for (int e = 0; e < 4; ++e) wvv[e] = wv[(c2 + e) * D + t];
#pragma unroll
    for (int jj = 0; jj < 8; ++jj) {
      F4 x; x.v = *(const float4*)&nl[jj][c2];
#pragma unroll
      for (int e = 0; e < 4; ++e) acc[jj] = fmaf(x.f[e], wvv[e], acc[jj]);
    }
  }
  const float bias = bv[t];
#pragma unroll
  for (int jj = 0; jj < 8; ++jj)
    Vf[(b * N + j0 + jj) * D + t] = acc[jj] + bias;

  // aq/ak: 8 rows x 16 outputs (aq[8] | ak[8]) on the first 128 threads
  if (t < 128) {
    const int il = t >> 4, oi = t & 15;
    float s = 0.f;
    for (int c = 0; c < D; ++c) s = fmaf(nl[il][c], FQK[c * 16 + oi], s);
    s += BF[oi];
    if (oi < 8) AQ[(b * H + oi) * N + j0 + il] = s;
    else        AK[(b * H + (oi - 8)) * N + j0 + il] = s;
  }
}

// K4: fused edge-MLP (P1+P2+eb1 -> LN -> ReLU -> dot V2) -> scores -> softmax
//     -> attn write -> ctx = attn @ v -> out = ctx @ wo + bo.
// grid: B*32 blocks (one per (b, 4-row i-tile)); 256 threads: j = t&127, ip = t>>7
// (half-block ip handles rows ii = 2*ip, 2*ip+1).
__global__ __launch_bounds__(256) void k4_attn(
    const float* __restrict__ ws,
    const float* __restrict__ eb1, const float* __restrict__ ln_g,
    const float* __restrict__ ln_b, const float* __restrict__ attn_bp,
    const float* __restrict__ wo, const float* __restrict__ bo,
    float* __restrict__ outp, float* __restrict__ attnp) {
  const int bid = blockIdx.x;
  const int b = bid >> 5;
  const int i0 = (bid & 31) * 4;
  const int t = threadIdx.x;
  const int j = t & 127;
  const int ip = t >> 7;

  __shared__ float eb1s[D], gs[D], bs[D];
  __shared__ float v2s[H * D];
  __shared__ float p1s[4 * D];
  __shared__ float aqs[32];
  __shared__ float attns[4][H][N];
  __shared__ float ctxs[4 * D];
  __shared__ float red[4][16];

  const float* P1Tf = ws + WS_P1T;
  const float* Vf   = ws + WS_V;
  const float* AQ   = ws + WS_AQ;
  const float* AK   = ws + WS_AK;
  const float* BF   = ws + WS_BF;
  const float* V2T  = ws + WS_V2;

  eb1s[t] = eb1[t]; gs[t] = ln_g[t]; bs[t] = ln_b[t];
  for (int k = t; k < H * D; k += 256) v2s[k] = V2T[k];
  for (int k = t; k < 4 * D; k += 256) {
    const int c = k >> 2, ii = k & 3;
    const int idx = i0 + ii - 1;
    p1s[ii * D + c] = (idx >= 0)
        ? P1Tf[(b * 64 + (c >> 2)) * 512 + idx * 4 + (c & 3)] : 0.f;
  }
  if (t < 32) aqs[t] = AQ[(b * H + (t & 7)) * N + i0 + (t >> 3)];
  float akr[8], befr[8];
#pragma unroll
  for (int h = 0; h < 8; ++h) {
    akr[h] = AK[(b * H + h) * N + j];
    befr[h] = BF[16 + h];
  }
  const float attnb = attn_bp[0];
  __syncthreads();

  const int jm1 = (j == 0) ? 0 : j - 1;
  const bool row0 = (i0 == 0) && (ip == 0);  // row i==0 needs per-lane P1[j-1]
  const float4* P14 = reinterpret_cast<const float4*>(ws + WS_P1T);
  const float4* P24 = reinterpret_cast<const float4*>(ws + WS_P2T);
  const int base4 = b * 64 * 128;

  // pass 1: LayerNorm stats (per lane: rows ii = 2*ip, 2*ip+1)
  float sum[2] = {0.f, 0.f}, sq[2] = {0.f, 0.f};
  for (int c4 = 0; c4 < 64; ++c4) {
    F4 p2; p2.v = P24[base4 + c4 * 128 + jm1];
    F4 e4; e4.v = *(const float4*)&eb1s[c4 * 4];
    F4 p1[2];
    if (row0) p1[0].v = P14[base4 + c4 * 128 + jm1];
    else      p1[0].v = *(const float4*)&p1s[(ip * 2 + 0) * D + c4 * 4];
    p1[1].v = *(const float4*)&p1s[(ip * 2 + 1) * D + c4 * 4];
#pragma unroll
    for (int kk = 0; kk < 2; ++kk) {
#pragma unroll
      for (int e = 0; e < 4; ++e) {
        const float u = p1[kk].f[e] + p2.f[e] + e4.f[e];
        sum[kk] += u;
        sq[kk] = fmaf(u, u, sq[kk]);
      }
    }
  }
  float mean[2], rstd[2];
#pragma unroll
  for (int kk = 0; kk < 2; ++kk) {
    mean[kk] = sum[kk] * (1.f / 256.f);
    const float var = sq[kk] * (1.f / 256.f) - mean[kk] * mean[kk];
    rstd[kk] = 1.f / sqrtf(var + LN_EPS);
  }

  // pass 2: ReLU(LN(u)) dotted with folded V2 -> ae per head
  float dot[2][8];
#pragma unroll
  for (int kk = 0; kk < 2; ++kk)
#pragma unroll
    for (int h = 0; h < 8; ++h) dot[kk][h] = 0.f;
  for (int c4 = 0; c4 < 64; ++c4) {
    F4 p2; p2.v = P24[base4 + c4 * 128 + jm1];
    F4 e4; e4.v = *(const float4*)&eb1s[c4 * 4];
    F4 g4; g4.v = *(const float4*)&gs[c4 * 4];
    F4 b4; b4.v = *(const float4*)&bs[c4 * 4];
    F4 p1[2];
    if (row0) p1[0].v = P14[base4 + c4 * 128 + jm1];
    else      p1[0].v = *(const float4*)&p1s[(ip * 2 + 0) * D + c4 * 4];
    p1[1].v = *(const float4*)&p1s[(ip * 2 + 1) * D + c4 * 4];
    float w[2][4];
#pragma unroll
    for (int kk = 0; kk < 2; ++kk) {
#pragma unroll
      for (int e = 0; e < 4; ++e) {
        const float u = p1[kk].f[e] + p2.f[e] + e4.f[e];
        const float z = fmaf((u - mean[kk]) * rstd[kk], g4.f[e], b4.f[e]);
        w[kk][e] = fmaxf(z, 0.f);
      }
    }
#pragma unroll
    for (int h = 0; h < 8; ++h) {
      F4 v2v; v2v.v = *(const float4*)&v2s[h * D + c4 * 4];
#pragma unroll
      for (int kk = 0; kk < 2; ++kk) {
        float d0 = fmaf(w[kk][0], v2v.f[0], dot[kk][h]);
        float d1 = fmaf(w[kk][1], v2v.f[1], d0);
        float d2 = fmaf(w[kk][2], v2v.f[2], d1);
        dot[kk][h] = fmaf(w[kk][3], v2v.f[3], d2);
      }
    }
  }

  // scores (masked -> -inf so exp underflows to exact 0 like the reference)
  float sc[2][8];
#pragma unroll
  for (int kk = 0; kk < 2; ++kk) {
    const int i = i0 + ip * 2 + kk;
    const bool masked = (j == 0) || (j == i);
#pragma unroll
    for (int h = 0; h < 8; ++h) {
      const float v = aqs[(ip * 2 + kk) * 8 + h] + akr[h] + befr[h] + attnb + dot[kk][h];
      sc[kk][h] = masked ? -INFINITY : v;
    }
  }

  // softmax over j (128 lanes = waves {2*ip, 2*ip+1})
  const int wvid = t >> 6;
  float mx[2][8];
#pragma unroll
  for (int kk = 0; kk < 2; ++kk)
#pragma unroll
    for (int h = 0; h < 8; ++h) {
      float v = sc[kk][h];
#pragma unroll
      for (int o = 1; o < 64; o <<= 1) v = fmaxf(v, __shfl_xor(v, o));
      mx[kk][h] = v;
    }
  if ((t & 63) == 0) {
#pragma unroll
    for (int kk = 0; kk < 2; ++kk)
#pragma unroll
      for (int h = 0; h < 8; ++h) red[wvid][kk * 8 + h] = mx[kk][h];
  }
  __syncthreads();
#pragma unroll
  for (int kk = 0; kk < 2; ++kk)
#pragma unroll
    for (int h = 0; h < 8; ++h)
      mx[kk][h] = fmaxf(red[ip * 2][kk * 8 + h], red[ip * 2 + 1][kk * 8 + h]);
  __syncthreads();

  float pr[2][8], sm[2][8];
#pragma unroll
  for (int kk = 0; kk < 2; ++kk)
#pragma unroll
    for (int h = 0; h < 8; ++h) {
      pr[kk][h] = expf(sc[kk][h] - mx[kk][h]);
      float v = pr[kk][h];
#pragma unroll
      for (int o = 1; o < 64; o <<= 1) v += __shfl_xor(v, o);
      sm[kk][h] = v;
    }
  if ((t & 63) == 0) {
#pragma unroll
    for (int kk = 0; kk < 2; ++kk)
#pragma unroll
      for (int h = 0; h < 8; ++h) red[wvid][kk * 8 + h] = sm[kk][h];
  }
  __syncthreads();
#pragma unroll
  for (int kk = 0; kk < 2; ++kk) {
    const int i = i0 + ip * 2 + kk;
#pragma unroll
    for (int h = 0; h < 8; ++h) {
      const float denom = red[ip * 2][kk * 8 + h] + red[ip * 2 + 1][kk * 8 + h];
      const float at = pr[kk][h] / denom;
      attns[ip * 2 + kk][h][j] = at;
      attnp[((b * H + h) * N + i) * N + j] = at;
    }
  }
  __syncthreads();

  // ctx = attn @ v : thread = channel c = t, h = t>>5
  float vctx[4] = {0.f, 0.f, 0.f, 0.f};
  const int hh = t >> 5;
  for (int jj = 0; jj < N; ++jj) {
    const float vv = Vf[(b * N + jj) * D + t];
#pragma unroll
    for (int ii = 0; ii < 4; ++ii) vctx[ii] = fmaf(attns[ii][hh][jj], vv, vctx[ii]);
  }
#pragma unroll
  for (int ii = 0; ii < 4; ++ii) ctxs[ii * D + t] = vctx[ii];
  __syncthreads();

  // out = ctx @ wo + bo
  float acc[4];
#pragma unroll
  for (int ii = 0; ii < 4; ++ii) acc[ii] = bo[t];
  for (int c2 = 0; c2 < D; c2 += 4) {
    const float w0 = wo[(c2 + 0) * D + t];
    const float w1 = wo[(c2 + 1) * D + t];
    const float w2 = wo[(c2 + 2) * D + t];
    const float w3 = wo[(c2 + 3) * D + t];
#pragma unroll
    for (int ii = 0; ii < 4; ++ii) {
      F4 cx; cx.v = *(const float4*)&ctxs[ii * D + c2];
      acc[ii] = fmaf(cx.f[0], w0, acc[ii]);
      acc[ii] = fmaf(cx.f[1], w1, acc[ii]);
      acc[ii] = fmaf(cx.f[2], w2, acc[ii]);
      acc[ii] = fmaf(cx.f[3], w3, acc[ii]);
    }
  }
#pragma unroll
  for (int ii = 0; ii < 4; ++ii)
    outp[(b * N + i0 + ii) * D + t] = acc[ii];
}

extern "C" void kernel_launch(void* const* d_in, const int* in_sizes, int n_in,
                              void* d_out, int out_size, void* d_ws, size_t ws_size,
                              hipStream_t stream) {
  (void)in_sizes; (void)n_in; (void)out_size; (void)ws_size;
  const float* desc = (const float*)d_in[0];
  const float* nv   = (const float*)d_in[1];
  const float* wq   = (const float*)d_in[2];
  const float* bq   = (const float*)d_in[3];
  const float* wk   = (const float*)d_in[4];
  const float* bk   = (const float*)d_in[5];
  const float* wv   = (const float*)d_in[6];
  const float* bv   = (const float*)d_in[7];
  const float* ew1  = (const float*)d_in[8];
  const float* eb1  = (const float*)d_in[9];
  const float* ln_g = (const float*)d_in[10];
  const float* ln_b = (const float*)d_in[11];
  const float* ew2  = (const float*)d_in[12];
  const float* eb2  = (const float*)d_in[13];
  const float* aw   = (const float*)d_in[14];
  const float* ab   = (const float*)d_in[15];
  const float* wo   = (const float*)d_in[16];
  const float* bo   = (const float*)d_in[17];

  float* ws   = (float*)d_ws;
  float* outp = (float*)d_out;
  float* attnp = outp + B * N * D;

  k1_fold<<<3, 256, 0, stream>>>(wq, wk, ew2, bq, bk, eb2, aw, ws);
  k2_pmat<<<B * 16, 256, 0, stream>>>(desc, ew1, ws);
  k3_qkv<<<B * 16, 256, 0, stream>>>(nv, wv, bv, ws);
  k4_attn<<<B * 32, 256, 0, stream>>>(ws, eb1, ln_g, ln_b, ab, wo, bo, outp, attnp);
}

// Round 2
// 123.165 us; speedup vs baseline: 1.1001x; 1.1001x over previous
//
#include <hip/hip_runtime.h>
#include <math.h>

namespace {
constexpr int D = 256;
constexpr int H = 8;
constexpr int HD = 32;
constexpr int B = 8;
constexpr int S = 127;
constexpr int N = 128;
constexpr float LN_EPS = 1e-5f;

// ws layout (float offsets). P1T/P2T are stored PACKED:
// element (b, c, i) at (b*64 + (c>>2))*512 + i*4 + (c&3)  -> float4 over c for fixed i.
constexpr int WS_P1T = 0;                  // B*D*N
constexpr int WS_P2T = WS_P1T + B * D * N; // B*D*N
constexpr int WS_V   = WS_P2T + B * D * N; // B*N*D (row-major)
constexpr int WS_AQ  = WS_V + B * N * D;   // B*H*N
constexpr int WS_AK  = WS_AQ + B * H * N;  // B*H*N
constexpr int WS_FQK = WS_AK + B * H * N;  // D*16 (wq-fold | wk-fold)
constexpr int WS_V2  = WS_FQK + D * 16;    // H*D (transposed: [h][c])
constexpr int WS_BF  = WS_V2 + D * H;      // 32 (bq-fold[8], bk-fold[8], be-fold[8])

union F4 { float4 v; float f[4]; };
} // namespace

// K1: fold wq/wk with attn_w[:32]/[32:64] -> FQK (D x 16), ew2 with attn_w[64:96]
// -> V2T (H x D), plus bias folds. Thread-per-output: 6144 matrix outs + 24 bias outs.
__global__ __launch_bounds__(256) void k1_fold(
    const float* __restrict__ wq, const float* __restrict__ wk,
    const float* __restrict__ ew2, const float* __restrict__ bq,
    const float* __restrict__ bk, const float* __restrict__ eb2,
    const float* __restrict__ attn_w, float* __restrict__ ws) {
  float* FQK = ws + WS_FQK;
  float* V2T = ws + WS_V2;
  float* BF  = ws + WS_BF;
  const int tg = blockIdx.x * 256 + threadIdx.x;
  if (tg < 6144) {
    const int mat = tg >> 11;
    const int rem = tg & 2047;
    const int c = rem >> 3;
    const int h = rem & 7;
    const float* W = (mat == 0) ? wq : (mat == 1) ? wk : ew2;
    const float* aw = attn_w + mat * HD;
    const float* wrow = W + c * D + h * HD;
    float s = 0.f;
#pragma unroll
    for (int d = 0; d < HD; ++d) s = fmaf(wrow[d], aw[d], s);
    if (mat < 2) FQK[c * 16 + mat * 8 + h] = s;
    else         V2T[h * D + c] = s;
  } else if (tg < 6168) {
    const int idx = tg - 6144;
    const int mat = idx >> 3;
    const int h = idx & 7;
    const float* bias = (mat == 0) ? bq : (mat == 1) ? bk : eb2;
    const float* aw = attn_w + mat * HD;
    float s = 0.f;
#pragma unroll
    for (int d = 0; d < HD; ++d) s = fmaf(bias[h * HD + d], aw[d], s);
    BF[mat * 8 + h] = s;
  }
}

// KA: merged P-matrices (role 0, blocks 0..255) and V/aq/ak (role 1, blocks 256..511).
// Each block handles 4 rows, 256 threads (thread = output channel).
__global__ __launch_bounds__(256) void kA_pre(
    const float* __restrict__ desc, const float* __restrict__ ew1,
    const float* __restrict__ nv, const float* __restrict__ wv,
    const float* __restrict__ bv, float* __restrict__ ws) {
  const int blk = blockIdx.x;
  const int t = threadIdx.x;
  __shared__ float rows[4][264];
  __shared__ float aqred[4][64];

  if (blk < 256) {
    // ---- role 0: P1 = desc @ ew1[:D], P2 = desc @ ew1[D:], packed-transposed ----
    float* P1Tf = ws + WS_P1T;
    float* P2Tf = ws + WS_P2T;
    const int b = blk >> 5;
    const int i0 = (blk & 31) * 4;
    for (int k = t; k < 4 * D; k += 256) {
      const int r = k >> 8, c = k & (D - 1);
      const int row = i0 + r;
      rows[r][c] = (row < S) ? desc[(b * S + row) * D + c] : 0.f;
    }
    __syncthreads();
    float a1[4], a2[4];
#pragma unroll
    for (int ii = 0; ii < 4; ++ii) { a1[ii] = 0.f; a2[ii] = 0.f; }
    for (int c2 = 0; c2 < D; c2 += 4) {
      float w1[4], w2[4];
#pragma unroll
      for (int e = 0; e < 4; ++e) {
        w1[e] = ew1[(c2 + e) * D + t];
        w2[e] = ew1[(D + c2 + e) * D + t];
      }
#pragma unroll
      for (int ii = 0; ii < 4; ++ii) {
        F4 dv; dv.v = *(const float4*)&rows[ii][c2];
#pragma unroll
        for (int e = 0; e < 4; ++e) {
          a1[ii] = fmaf(dv.f[e], w1[e], a1[ii]);
          a2[ii] = fmaf(dv.f[e], w2[e], a2[ii]);
        }
      }
    }
    const int pbase = (b * 64 + (t >> 2)) * 512 + (t & 3);
#pragma unroll
    for (int ii = 0; ii < 4; ++ii) {
      if (i0 + ii < S) {
        P1Tf[pbase + (i0 + ii) * 4] = a1[ii];
        P2Tf[pbase + (i0 + ii) * 4] = a2[ii];
      }
    }
  } else {
    // ---- role 1: v = nv @ wv + bv, aq/ak via folded FQK ----
    float* Vf  = ws + WS_V;
    float* AQ  = ws + WS_AQ;
    float* AK  = ws + WS_AK;
    const float* FQK = ws + WS_FQK;
    const float* BF  = ws + WS_BF;
    const int blk2 = blk - 256;
    const int b = blk2 >> 5;
    const int j0 = (blk2 & 31) * 4;
    for (int k = t; k < 4 * D; k += 256) {
      const int r = k >> 8, c = k & (D - 1);
      rows[r][c] = nv[(b * N + j0 + r) * D + c];
    }
    __syncthreads();
    float acc[4];
#pragma unroll
    for (int jj = 0; jj < 4; ++jj) acc[jj] = 0.f;
    for (int c2 = 0; c2 < D; c2 += 4) {
      float wvv[4];
#pragma unroll
      for (int e = 0; e < 4; ++e) wvv[e] = wv[(c2 + e) * D + t];
#pragma unroll
      for (int jj = 0; jj < 4; ++jj) {
        F4 x; x.v = *(const float4*)&rows[jj][c2];
#pragma unroll
        for (int e = 0; e < 4; ++e) acc[jj] = fmaf(x.f[e], wvv[e], acc[jj]);
      }
    }
    const float bias = bv[t];
#pragma unroll
    for (int jj = 0; jj < 4; ++jj)
      Vf[(b * N + j0 + jj) * D + t] = acc[jj] + bias;

    // aq/ak: 4 rows x 16 outputs, split 4-way over channels, LDS-reduced.
    const int pair = t & 63;        // (row il, output oi)
    const int cq = t >> 6;          // channel quarter
    const int il = pair >> 4, oi = pair & 15;
    float s = 0.f;
    for (int c = cq * 64; c < cq * 64 + 64; ++c)
      s = fmaf(rows[il][c], FQK[c * 16 + oi], s);
    aqred[cq][pair] = s;
    __syncthreads();
    if (t < 64) {
      const int il2 = t >> 4, oi2 = t & 15;
      float s2 = aqred[0][t] + aqred[1][t] + aqred[2][t] + aqred[3][t] + BF[oi2];
      if (oi2 < 8) AQ[(b * H + oi2) * N + j0 + il2] = s2;
      else         AK[(b * H + (oi2 - 8)) * N + j0 + il2] = s2;
    }
  }
}

// K4: fused edge-MLP (P1+P2+eb1 -> LN -> ReLU -> dot V2) -> scores -> softmax
//     -> attn write -> ctx = attn @ v -> out = ctx @ wo + bo.
// grid: B*128 blocks (one per (b, i)); 256 threads: jl = t&127, cp = t>>7 is the
// channel half (channels [cp*128, cp*128+128)).
__global__ __launch_bounds__(256) void k4_attn(
    const float* __restrict__ ws,
    const float* __restrict__ eb1, const float* __restrict__ ln_g,
    const float* __restrict__ ln_b, const float* __restrict__ attn_bp,
    const float* __restrict__ wo, const float* __restrict__ bo,
    float* __restrict__ outp, float* __restrict__ attnp) {
  const int bid = blockIdx.x;
  const int b = bid >> 7;
  const int i = bid & 127;
  const int t = threadIdx.x;
  const int jl = t & 127;
  const int cp = t >> 7;

  __shared__ float eb1s[D], gs[D], bs[D];
  __shared__ float v2s[H * D];
  __shared__ float p1row[D];
  __shared__ float red1[2][128], red2[2][128];
  __shared__ float dsh[2][128][8];
  __shared__ float attn_sh[H][N];
  __shared__ float ctxs[D];
  __shared__ float aqs[8];
  __shared__ float redm[2][8], reds[2][8];

  const float* P1Tf = ws + WS_P1T;
  const float* Vf   = ws + WS_V;
  const float* AQ   = ws + WS_AQ;
  const float* AK   = ws + WS_AK;
  const float* BF   = ws + WS_BF;
  const float* V2T  = ws + WS_V2;

  eb1s[t] = eb1[t]; gs[t] = ln_g[t]; bs[t] = ln_b[t];
  for (int k = t; k < H * D; k += 256) v2s[k] = V2T[k];
  {
    const int idx = i - 1;
    p1row[t] = (idx >= 0)
        ? P1Tf[(b * 64 + (t >> 2)) * 512 + idx * 4 + (t & 3)] : 0.f;
  }
  if (t < 8) aqs[t] = AQ[(b * H + t) * N + i];
  float akr[8], befr[8];
#pragma unroll
  for (int h = 0; h < 8; ++h) {
    akr[h] = AK[(b * H + h) * N + jl];
    befr[h] = BF[16 + h];
  }
  const float attnb = attn_bp[0];
  __syncthreads();

  const int jm1 = (jl == 0) ? 0 : jl - 1;
  const bool row0 = (i == 0);  // row i==0 needs per-lane P1[j-1]
  const float4* P14 = reinterpret_cast<const float4*>(ws + WS_P1T);
  const float4* P24 = reinterpret_cast<const float4*>(ws + WS_P2T);
  const int base4 = b * 64 * 128;
  const int c4lo = cp * 32, c4hi = c4lo + 32;

  // pass 1: LayerNorm stats over this half's 128 channels
  float psum = 0.f, psq = 0.f;
  for (int c4 = c4lo; c4 < c4hi; ++c4) {
    F4 p2; p2.v = P24[base4 + c4 * 128 + jm1];
    F4 e4; e4.v = *(const float4*)&eb1s[c4 * 4];
    F4 p1;
    if (row0) p1.v = P14[base4 + c4 * 128 + jm1];
    else      p1.v = *(const float4*)&p1row[c4 * 4];
#pragma unroll
    for (int e = 0; e < 4; ++e) {
      const float u = p1.f[e] + p2.f[e] + e4.f[e];
      psum += u;
      psq = fmaf(u, u, psq);
    }
  }
  red1[cp][jl] = psum;
  red2[cp][jl] = psq;
  __syncthreads();
  const float tsum = red1[0][jl] + red1[1][jl];
  const float tsq  = red2[0][jl] + red2[1][jl];
  const float mean = tsum * (1.f / 256.f);
  const float var  = tsq * (1.f / 256.f) - mean * mean;
  const float rstd = 1.f / sqrtf(var + LN_EPS);

  // pass 2: ReLU(LN(u)) dotted with folded V2 (this half's channels)
  float dot[8];
#pragma unroll
  for (int h = 0; h < 8; ++h) dot[h] = 0.f;
  for (int c4 = c4lo; c4 < c4hi; ++c4) {
    F4 p2; p2.v = P24[base4 + c4 * 128 + jm1];
    F4 e4; e4.v = *(const float4*)&eb1s[c4 * 4];
    F4 g4; g4.v = *(const float4*)&gs[c4 * 4];
    F4 b4; b4.v = *(const float4*)&bs[c4 * 4];
    F4 p1;
    if (row0) p1.v = P14[base4 + c4 * 128 + jm1];
    else      p1.v = *(const float4*)&p1row[c4 * 4];
    float w4[4];
#pragma unroll
    for (int e = 0; e < 4; ++e) {
      const float u = p1.f[e] + p2.f[e] + e4.f[e];
      const float z = fmaf((u - mean) * rstd, g4.f[e], b4.f[e]);
      w4[e] = fmaxf(z, 0.f);
    }
#pragma unroll
    for (int h = 0; h < 8; ++h) {
      F4 v2v; v2v.v = *(const float4*)&v2s[h * D + c4 * 4];
      float d0 = fmaf(w4[0], v2v.f[0], dot[h]);
      float d1 = fmaf(w4[1], v2v.f[1], d0);
      float d2 = fmaf(w4[2], v2v.f[2], d1);
      dot[h] = fmaf(w4[3], v2v.f[3], d2);
    }
  }
#pragma unroll
  for (int h = 0; h < 8; ++h) dsh[cp][jl][h] = dot[h];
  __syncthreads();

  // scores + softmax over j on the first 128 lanes (2 waves)
  float sc[8], pr[8];
  if (t < 128) {
    const bool masked = (jl == 0) || (jl == i);
#pragma unroll
    for (int h = 0; h < 8; ++h) {
      const float v = aqs[h] + akr[h] + befr[h] + attnb
                      + dsh[0][jl][h] + dsh[1][jl][h];
      sc[h] = masked ? -INFINITY : v;
    }
    float mx[8];
#pragma unroll
    for (int h = 0; h < 8; ++h) {
      float v = sc[h];
#pragma unroll
      for (int o = 1; o < 64; o <<= 1) v = fmaxf(v, __shfl_xor(v, o));
      mx[h] = v;
    }
    if ((t & 63) == 0) {
#pragma unroll
      for (int h = 0; h < 8; ++h) redm[t >> 6][h] = mx[h];
    }
  }
  __syncthreads();
  if (t < 128) {
#pragma unroll
    for (int h = 0; h < 8; ++h) {
      const float m = fmaxf(redm[0][h], redm[1][h]);
      pr[h] = expf(sc[h] - m);
    }
    float sm[8];
#pragma unroll
    for (int h = 0; h < 8; ++h) {
      float v = pr[h];
#pragma unroll
      for (int o = 1; o < 64; o <<= 1) v += __shfl_xor(v, o);
      sm[h] = v;
    }
    if ((t & 63) == 0) {
#pragma unroll
      for (int h = 0; h < 8; ++h) reds[t >> 6][h] = sm[h];
    }
  }
  __syncthreads();
  if (t < 128) {
#pragma unroll
    for (int h = 0; h < 8; ++h) {
      const float at = pr[h] / (reds[0][h] + reds[1][h]);
      attn_sh[h][jl] = at;
      attnp[((b * H + h) * N + i) * N + jl] = at;
    }
  }
  __syncthreads();

  // ctx = attn @ v : thread = channel c = t, head = t>>5
  float acc = 0.f;
  const int hh = t >> 5;
  const float* Vb = Vf + b * N * D + t;
  for (int jj = 0; jj < N; ++jj)
    acc = fmaf(attn_sh[hh][jj], Vb[jj * D], acc);
  ctxs[t] = acc;
  __syncthreads();

  // out = ctx @ wo + bo
  float o = bo[t];
  for (int c2 = 0; c2 < D; c2 += 4) {
    F4 cx; cx.v = *(const float4*)&ctxs[c2];
    o = fmaf(cx.f[0], wo[(c2 + 0) * D + t], o);
    o = fmaf(cx.f[1], wo[(c2 + 1) * D + t], o);
    o = fmaf(cx.f[2], wo[(c2 + 2) * D + t], o);
    o = fmaf(cx.f[3], wo[(c2 + 3) * D + t], o);
  }
  outp[(b * N + i) * D + t] = o;
}

extern "C" void kernel_launch(void* const* d_in, const int* in_sizes, int n_in,
                              void* d_out, int out_size, void* d_ws, size_t ws_size,
                              hipStream_t stream) {
  (void)in_sizes; (void)n_in; (void)out_size; (void)ws_size;
  const float* desc = (const float*)d_in[0];
  const float* nv   = (const float*)d_in[1];
  const float* wq   = (const float*)d_in[2];
  const float* bq   = (const float*)d_in[3];
  const float* wk   = (const float*)d_in[4];
  const float* bk   = (const float*)d_in[5];
  const float* wv   = (const float*)d_in[6];
  const float* bv   = (const float*)d_in[7];
  const float* ew1  = (const float*)d_in[8];
  const float* eb1  = (const float*)d_in[9];
  const float* ln_g = (const float*)d_in[10];
  const float* ln_b = (const float*)d_in[11];
  const float* ew2  = (const float*)d_in[12];
  const float* eb2  = (const float*)d_in[13];
  const float* aw   = (const float*)d_in[14];
  const float* ab   = (const float*)d_in[15];
  const float* wo   = (const float*)d_in[16];
  const float* bo   = (const float*)d_in[17];

  float* ws   = (float*)d_ws;
  float* outp = (float*)d_out;
  float* attnp = outp + B * N * D;

  k1_fold<<<25, 256, 0, stream>>>(wq, wk, ew2, bq, bk, eb2, aw, ws);
  kA_pre<<<512, 256, 0, stream>>>(desc, ew1, nv, wv, bv, ws);
  k4_attn<<<B * 128, 256, 0, stream>>>(ws, eb1, ln_g, ln_b, ab, wo, bo, outp, attnp);
}